// Round 1
// baseline (1026.401 us; speedup 1.0000x reference)
//
#include <hip/hip_runtime.h>
#include <math.h>
#include <stdint.h>

#define NLEVELS 16
#define TSIZE (1u << 19)
#define HMASK (TSIZE - 1u)
#define P1 2654435761u
#define P2 805459861u

struct LevelParams { float cell[NLEVELS]; };

// thread t = point*16 + level. Output float2 store at index t is fully coalesced.
__global__ __launch_bounds__(256) void hashgrid_kernel(
    const float* __restrict__ xyz,
    const float* __restrict__ tables,
    float2* __restrict__ out,
    LevelParams lp,
    unsigned int total)
{
    unsigned int t = blockIdx.x * 256u + threadIdx.x;
    if (t >= total) return;
    unsigned int n = t >> 4;
    unsigned int l = t & 15u;

    float x = xyz[n * 3 + 0];
    float y = xyz[n * 3 + 1];
    float z = xyz[n * 3 + 2];

    float cell = lp.cell[l];   // lanes 0..15 span the 64B cell[] line -> 1 line/wave

    // min_index = floor((x - 0) / cell): IEEE correctly-rounded f32 division
    // (HIP default) — must match numpy bit-for-bit for the floor decision.
    float fx = floorf(x / cell);
    float fy = floorf(y / cell);
    float fz = floorf(z / cell);

    float mvx = fx * cell, mvy = fy * cell, mvz = fz * cell;
    // denom = (min_v + cell) - min_v, exactly as the reference computes it
    float dnx = (mvx + cell) - mvx;
    float dny = (mvy + cell) - mvy;
    float dnz = (mvz + cell) - mvz;

    // Interp weights: 1-ulp rcp is plenty (output error ~1e-11 vs 2e-6 thresh)
    float dx = (x - mvx) * __builtin_amdgcn_rcpf(dnx);
    float dy = (y - mvy) * __builtin_amdgcn_rcpf(dny);
    float dz = (z - mvz) * __builtin_amdgcn_rcpf(dnz);

    unsigned int ix = (unsigned int)(int)fx;
    unsigned int iy = (unsigned int)(int)fy;
    unsigned int iz = (unsigned int)(int)fz;

    // primes = {1, P1, P2}; (i+1)*P == i*P + P mod 2^32
    unsigned int hx0 = ix,      hx1 = ix + 1u;
    unsigned int hy0 = iy * P1, hy1 = hy0 + P1;
    unsigned int hz0 = iz * P2, hz1 = hz0 + P2;

    const float2* __restrict__ tab = (const float2*)tables + (size_t)l * TSIZE;

    // vertex order: v = (xbit<<2)|(ybit<<1)|zbit
    float2 e0 = tab[(hx0 ^ hy0 ^ hz0) & HMASK];
    float2 e1 = tab[(hx0 ^ hy0 ^ hz1) & HMASK];
    float2 e2 = tab[(hx0 ^ hy1 ^ hz0) & HMASK];
    float2 e3 = tab[(hx0 ^ hy1 ^ hz1) & HMASK];
    float2 e4 = tab[(hx1 ^ hy0 ^ hz0) & HMASK];
    float2 e5 = tab[(hx1 ^ hy0 ^ hz1) & HMASK];
    float2 e6 = tab[(hx1 ^ hy1 ^ hz0) & HMASK];
    float2 e7 = tab[(hx1 ^ hy1 ^ hz1) & HMASK];

    float wx0 = 1.0f - dx, wy0 = 1.0f - dy, wz0 = 1.0f - dz;

    float c00x = e0.x * wx0 + e4.x * dx;
    float c00y = e0.y * wx0 + e4.y * dx;
    float c01x = e1.x * wx0 + e5.x * dx;
    float c01y = e1.y * wx0 + e5.y * dx;
    float c10x = e2.x * wx0 + e6.x * dx;
    float c10y = e2.y * wx0 + e6.y * dx;
    float c11x = e3.x * wx0 + e7.x * dx;
    float c11y = e3.y * wx0 + e7.y * dx;

    float c0x = c00x * wy0 + c10x * dy;
    float c0y = c00y * wy0 + c10y * dy;
    float c1x = c01x * wy0 + c11x * dy;
    float c1y = c01y * wy0 + c11y * dy;

    float rx = c0x * wz0 + c1x * dz;
    float ry = c0y * wz0 + c1y * dz;

    out[t] = make_float2(rx, ry);
}

extern "C" void kernel_launch(void* const* d_in, const int* in_sizes, int n_in,
                              void* d_out, int out_size, void* d_ws, size_t ws_size,
                              hipStream_t stream)
{
    const float* xyz    = (const float*)d_in[0];
    const float* tables = (const float*)d_in[1];
    float2* out = (float2*)d_out;

    // Resolutions via the SAME libm calls CPython's math module makes in this
    // container — bit-identical to the reference's module-level constants.
    LevelParams lp;
    double b = exp((log(512.0) - log(16.0)) / 15.0);
    for (int i = 0; i < NLEVELS; ++i) {
        int res = (int)floor(16.0 * pow(b, (double)i));
        lp.cell[i] = 1.0f / (float)res;   // fl32(1/res), matches (BB_MAX-BB_MIN)/res
    }

    unsigned int npts  = (unsigned int)(in_sizes[0] / 3);
    unsigned int total = npts * (unsigned int)NLEVELS;
    unsigned int blocks = (total + 255u) / 256u;

    hipLaunchKernelGGL(hashgrid_kernel, dim3(blocks), dim3(256), 0, stream,
                       xyz, tables, out, lp, total);
}

// Round 2
// 890.696 us; speedup vs baseline: 1.1524x; 1.1524x over previous
//
#include <hip/hip_runtime.h>
#include <math.h>
#include <stdint.h>

#define NLEVELS 16
#define TSIZE   (1u << 19)
#define HMASK   (TSIZE - 1u)
#define P1 2654435761u
#define P2 805459861u

typedef float v2f __attribute__((ext_vector_type(2)));
typedef float v4f __attribute__((ext_vector_type(4)));

struct LevelParams { float cell[NLEVELS]; };

__device__ __forceinline__ uint32_t bf16_rne(float f) {
    uint32_t b = __float_as_uint(f);
    return (b + 0x7FFFu + ((b >> 16) & 1u)) >> 16;   // round-to-nearest-even
}

// ---------------------------------------------------------------------------
// Phase 0: f32 tables -> packed bf16x2 (4 B/entry) in ws. Rebuilt every call
// (ws is re-poisoned). Entry u: hi16 = bf16(f0), lo16 = bf16(f1) so unpack is
// f0 = asfloat(u & 0xFFFF0000), f1 = asfloat(u << 16).
__global__ __launch_bounds__(256) void convert_tables_kernel(
    const v2f* __restrict__ tables, uint32_t* __restrict__ tab16,
    unsigned int nEntries)
{
    unsigned int i = blockIdx.x * 256u + threadIdx.x;
    if (i >= nEntries) return;
    v2f v = __builtin_nontemporal_load(&tables[i]);
    tab16[i] = (bf16_rne(v.x) << 16) | bf16_rne(v.y);
}

// ---------------------------------------------------------------------------
// Phase 1: compute, level-partitioned across XCDs.
// blockIdx%8 -> XCD (dispatch heuristic). XCD k runs level 8+k (full-table,
// random hash) for ALL points first, then coarse level k. During each phase
// the XCD's L2 holds exactly one 2 MiB bf16 table; xyz/stage traffic is
// non-temporal so it doesn't evict the table.
// Results land level-major in stage[l][n] (coalesced nt float2 stores).
__global__ __launch_bounds__(256) void hashgrid_compute_kernel(
    const float* __restrict__ xyz,
    const uint32_t* __restrict__ tab16,
    v2f* __restrict__ stage,
    LevelParams lp,
    unsigned int npts, unsigned int chunksPerLevel)
{
    unsigned int b   = blockIdx.x;
    unsigned int xcd = b & 7u;
    unsigned int j   = b >> 3;
    bool fine = (j < chunksPerLevel);
    unsigned int level = fine ? (8u + xcd) : xcd;
    unsigned int chunk = fine ? j : (j - chunksPerLevel);
    unsigned int n = chunk * 256u + threadIdx.x;   // one point per thread

    float x = __builtin_nontemporal_load(&xyz[n * 3 + 0]);
    float y = __builtin_nontemporal_load(&xyz[n * 3 + 1]);
    float z = __builtin_nontemporal_load(&xyz[n * 3 + 2]);

    float cell = lp.cell[level];   // block-uniform

    // floor(x / cell) with IEEE-correct f32 division (matches reference)
    float fx = floorf(x / cell);
    float fy = floorf(y / cell);
    float fz = floorf(z / cell);

    float mvx = fx * cell, mvy = fy * cell, mvz = fz * cell;
    float dnx = (mvx + cell) - mvx;
    float dny = (mvy + cell) - mvy;
    float dnz = (mvz + cell) - mvz;

    float dx = (x - mvx) * __builtin_amdgcn_rcpf(dnx);
    float dy = (y - mvy) * __builtin_amdgcn_rcpf(dny);
    float dz = (z - mvz) * __builtin_amdgcn_rcpf(dnz);

    unsigned int ix = (unsigned int)(int)fx;
    unsigned int iy = (unsigned int)(int)fy;
    unsigned int iz = (unsigned int)(int)fz;

    unsigned int hx0 = ix,      hx1 = ix + 1u;
    unsigned int hy0 = iy * P1, hy1 = hy0 + P1;
    unsigned int hz0 = iz * P2, hz1 = hz0 + P2;

    const uint32_t* __restrict__ tab = tab16 + (size_t)level * TSIZE;

    // vertex v = (xbit<<2)|(ybit<<1)|zbit ; these are the ONLY cached loads
    uint32_t u0 = tab[(hx0 ^ hy0 ^ hz0) & HMASK];
    uint32_t u1 = tab[(hx0 ^ hy0 ^ hz1) & HMASK];
    uint32_t u2 = tab[(hx0 ^ hy1 ^ hz0) & HMASK];
    uint32_t u3 = tab[(hx0 ^ hy1 ^ hz1) & HMASK];
    uint32_t u4 = tab[(hx1 ^ hy0 ^ hz0) & HMASK];
    uint32_t u5 = tab[(hx1 ^ hy0 ^ hz1) & HMASK];
    uint32_t u6 = tab[(hx1 ^ hy1 ^ hz0) & HMASK];
    uint32_t u7 = tab[(hx1 ^ hy1 ^ hz1) & HMASK];

    #define UX(u) __uint_as_float((u) & 0xFFFF0000u)
    #define UY(u) __uint_as_float((u) << 16)

    float wx0 = 1.0f - dx, wy0 = 1.0f - dy, wz0 = 1.0f - dz;

    float c00x = UX(u0) * wx0 + UX(u4) * dx;
    float c00y = UY(u0) * wx0 + UY(u4) * dx;
    float c01x = UX(u1) * wx0 + UX(u5) * dx;
    float c01y = UY(u1) * wx0 + UY(u5) * dx;
    float c10x = UX(u2) * wx0 + UX(u6) * dx;
    float c10y = UY(u2) * wx0 + UY(u6) * dx;
    float c11x = UX(u3) * wx0 + UX(u7) * dx;
    float c11y = UY(u3) * wx0 + UY(u7) * dx;

    #undef UX
    #undef UY

    float c0x = c00x * wy0 + c10x * dy;
    float c0y = c00y * wy0 + c10y * dy;
    float c1x = c01x * wy0 + c11x * dy;
    float c1y = c01y * wy0 + c11y * dy;

    v2f r;
    r.x = c0x * wz0 + c1x * dz;
    r.y = c0y * wz0 + c1y * dz;

    __builtin_nontemporal_store(r, &stage[(size_t)level * npts + n]);
}

// ---------------------------------------------------------------------------
// Phase 2: transpose stage[l][n] (level-major) -> out[n][l] (point-major).
// Loads are coalesced across lanes per level; each lane then owns one point's
// full 128 B record, stored as 8 float4 — the wave covers full lines, L2
// write-combines them (single XCD), so HBM sees full-line writes.
__global__ __launch_bounds__(256) void transpose_kernel(
    const v2f* __restrict__ stage, v4f* __restrict__ out4, unsigned int npts)
{
    unsigned int p = blockIdx.x * 256u + threadIdx.x;
    if (p >= npts) return;
    v2f r[NLEVELS];
#pragma unroll
    for (int l = 0; l < NLEVELS; ++l)
        r[l] = __builtin_nontemporal_load(&stage[(size_t)l * npts + p]);
#pragma unroll
    for (int k = 0; k < 8; ++k) {
        v4f w;
        w.x = r[2 * k].x;     w.y = r[2 * k].y;
        w.z = r[2 * k + 1].x; w.w = r[2 * k + 1].y;
        __builtin_nontemporal_store(w, &out4[(size_t)p * 8u + k]);
    }
}

// ---------------------------------------------------------------------------
// Fallback (round-1 kernel): direct f32 gathers, used only if ws is too small.
__global__ __launch_bounds__(256) void hashgrid_direct_kernel(
    const float* __restrict__ xyz,
    const float* __restrict__ tables,
    float2* __restrict__ out,
    LevelParams lp,
    unsigned int total)
{
    unsigned int t = blockIdx.x * 256u + threadIdx.x;
    if (t >= total) return;
    unsigned int n = t >> 4;
    unsigned int l = t & 15u;

    float x = xyz[n * 3 + 0], y = xyz[n * 3 + 1], z = xyz[n * 3 + 2];
    float cell = lp.cell[l];
    float fx = floorf(x / cell), fy = floorf(y / cell), fz = floorf(z / cell);
    float mvx = fx * cell, mvy = fy * cell, mvz = fz * cell;
    float dnx = (mvx + cell) - mvx, dny = (mvy + cell) - mvy, dnz = (mvz + cell) - mvz;
    float dx = (x - mvx) * __builtin_amdgcn_rcpf(dnx);
    float dy = (y - mvy) * __builtin_amdgcn_rcpf(dny);
    float dz = (z - mvz) * __builtin_amdgcn_rcpf(dnz);
    unsigned int ix = (unsigned int)(int)fx, iy = (unsigned int)(int)fy, iz = (unsigned int)(int)fz;
    unsigned int hx0 = ix, hx1 = ix + 1u;
    unsigned int hy0 = iy * P1, hy1 = hy0 + P1;
    unsigned int hz0 = iz * P2, hz1 = hz0 + P2;
    const float2* __restrict__ tab = (const float2*)tables + (size_t)l * TSIZE;
    float2 e0 = tab[(hx0 ^ hy0 ^ hz0) & HMASK];
    float2 e1 = tab[(hx0 ^ hy0 ^ hz1) & HMASK];
    float2 e2 = tab[(hx0 ^ hy1 ^ hz0) & HMASK];
    float2 e3 = tab[(hx0 ^ hy1 ^ hz1) & HMASK];
    float2 e4 = tab[(hx1 ^ hy0 ^ hz0) & HMASK];
    float2 e5 = tab[(hx1 ^ hy0 ^ hz1) & HMASK];
    float2 e6 = tab[(hx1 ^ hy1 ^ hz0) & HMASK];
    float2 e7 = tab[(hx1 ^ hy1 ^ hz1) & HMASK];
    float wx0 = 1.0f - dx, wy0 = 1.0f - dy, wz0 = 1.0f - dz;
    float c00x = e0.x * wx0 + e4.x * dx, c00y = e0.y * wx0 + e4.y * dx;
    float c01x = e1.x * wx0 + e5.x * dx, c01y = e1.y * wx0 + e5.y * dx;
    float c10x = e2.x * wx0 + e6.x * dx, c10y = e2.y * wx0 + e6.y * dx;
    float c11x = e3.x * wx0 + e7.x * dx, c11y = e3.y * wx0 + e7.y * dx;
    float c0x = c00x * wy0 + c10x * dy, c0y = c00y * wy0 + c10y * dy;
    float c1x = c01x * wy0 + c11x * dy, c1y = c01y * wy0 + c11y * dy;
    out[t] = make_float2(c0x * wz0 + c1x * dz, c0y * wz0 + c1y * dz);
}

// ---------------------------------------------------------------------------
extern "C" void kernel_launch(void* const* d_in, const int* in_sizes, int n_in,
                              void* d_out, int out_size, void* d_ws, size_t ws_size,
                              hipStream_t stream)
{
    const float* xyz    = (const float*)d_in[0];
    const float* tables = (const float*)d_in[1];

    // Resolutions via the SAME libm calls CPython makes (bit-exact floors;
    // verified passing in round 1).
    LevelParams lp;
    double bg = exp((log(512.0) - log(16.0)) / 15.0);
    for (int i = 0; i < NLEVELS; ++i) {
        int res = (int)floor(16.0 * pow(bg, (double)i));
        lp.cell[i] = 1.0f / (float)res;
    }

    unsigned int npts = (unsigned int)(in_sizes[0] / 3);
    size_t tabBytes   = (size_t)NLEVELS * TSIZE * 4u;        // 32 MiB
    size_t stageBytes = (size_t)npts * NLEVELS * sizeof(v2f); // 128 MiB

    if (ws_size >= tabBytes + stageBytes && (npts & 255u) == 0u) {
        uint32_t* tab16 = (uint32_t*)d_ws;
        v2f* stage = (v2f*)((char*)d_ws + tabBytes);

        unsigned int nEntries = NLEVELS * TSIZE;
        hipLaunchKernelGGL(convert_tables_kernel,
                           dim3((nEntries + 255u) / 256u), dim3(256), 0, stream,
                           (const v2f*)tables, tab16, nEntries);

        unsigned int chunks = npts / 256u;                  // 4096
        hipLaunchKernelGGL(hashgrid_compute_kernel,
                           dim3(NLEVELS * chunks), dim3(256), 0, stream,
                           xyz, tab16, stage, lp, npts, chunks);

        hipLaunchKernelGGL(transpose_kernel,
                           dim3(chunks), dim3(256), 0, stream,
                           stage, (v4f*)d_out, npts);
    } else {
        unsigned int total = npts * (unsigned int)NLEVELS;
        hipLaunchKernelGGL(hashgrid_direct_kernel,
                           dim3((total + 255u) / 256u), dim3(256), 0, stream,
                           xyz, tables, (float2*)d_out, lp, total);
    }
}

// Round 3
// 571.046 us; speedup vs baseline: 1.7974x; 1.5598x over previous
//
#include <hip/hip_runtime.h>
#include <math.h>
#include <stdint.h>

#define NLEVELS 16
#define TSIZE   (1u << 19)
#define HMASK   (TSIZE - 1u)
#define P1 2654435761u
#define P2 805459861u

typedef float v2f __attribute__((ext_vector_type(2)));
typedef float v4f __attribute__((ext_vector_type(4)));

struct LevelParams { float cell[NLEVELS]; };

__device__ __forceinline__ uint32_t bf16_rne(float f) {
    uint32_t b = __float_as_uint(f);
    return (b + 0x7FFFu + ((b >> 16) & 1u)) >> 16;   // round-to-nearest-even
}

// ---------------------------------------------------------------------------
// Phase 0: f32 tables -> packed bf16x2 (4 B/entry) in ws (rebuilt every call).
__global__ __launch_bounds__(256) void convert_tables_kernel(
    const v2f* __restrict__ tables, uint32_t* __restrict__ tab16,
    unsigned int nEntries)
{
    unsigned int i = blockIdx.x * 256u + threadIdx.x;
    if (i >= nEntries) return;
    v2f v = __builtin_nontemporal_load(&tables[i]);
    tab16[i] = (bf16_rne(v.x) << 16) | bf16_rne(v.y);
}

// ---------------------------------------------------------------------------
// Phase 1: compute, level-partitioned across XCDs (blockIdx%8 -> XCD).
// XCD k owns fine level 8+k and coarse level k, INTERLEAVED (j&1) so coarse
// VALU/L1 work fills the fine level's L2-request-stall bubbles. Each XCD's L2
// holds its own table(s); stage stores are nt (write-once, full-line
// coalesced); xyz uses cached loads so L3 absorbs the 16x re-read.
__global__ __launch_bounds__(256) void hashgrid_compute_kernel(
    const float* __restrict__ xyz,
    const uint32_t* __restrict__ tab16,
    v2f* __restrict__ stage,
    LevelParams lp,
    unsigned int npts)
{
    unsigned int b   = blockIdx.x;
    unsigned int xcd = b & 7u;
    unsigned int j   = b >> 3;
    unsigned int level = (j & 1u) ? xcd : (8u + xcd);  // even j: fine, odd: coarse
    unsigned int chunk = j >> 1;
    unsigned int n = chunk * 256u + threadIdx.x;

    float x = xyz[n * 3 + 0];
    float y = xyz[n * 3 + 1];
    float z = xyz[n * 3 + 2];

    float cell = lp.cell[level];   // block-uniform

    // floor(x / cell) with IEEE-correct f32 division (matches reference)
    float fx = floorf(x / cell);
    float fy = floorf(y / cell);
    float fz = floorf(z / cell);

    float mvx = fx * cell, mvy = fy * cell, mvz = fz * cell;
    float dnx = (mvx + cell) - mvx;
    float dny = (mvy + cell) - mvy;
    float dnz = (mvz + cell) - mvz;

    float dx = (x - mvx) * __builtin_amdgcn_rcpf(dnx);
    float dy = (y - mvy) * __builtin_amdgcn_rcpf(dny);
    float dz = (z - mvz) * __builtin_amdgcn_rcpf(dnz);

    unsigned int ix = (unsigned int)(int)fx;
    unsigned int iy = (unsigned int)(int)fy;
    unsigned int iz = (unsigned int)(int)fz;

    unsigned int hx0 = ix,      hx1 = ix + 1u;
    unsigned int hy0 = iy * P1, hy1 = hy0 + P1;
    unsigned int hz0 = iz * P2, hz1 = hz0 + P2;

    const uint32_t* __restrict__ tab = tab16 + (size_t)level * TSIZE;

    uint32_t u0 = tab[(hx0 ^ hy0 ^ hz0) & HMASK];
    uint32_t u1 = tab[(hx0 ^ hy0 ^ hz1) & HMASK];
    uint32_t u2 = tab[(hx0 ^ hy1 ^ hz0) & HMASK];
    uint32_t u3 = tab[(hx0 ^ hy1 ^ hz1) & HMASK];
    uint32_t u4 = tab[(hx1 ^ hy0 ^ hz0) & HMASK];
    uint32_t u5 = tab[(hx1 ^ hy0 ^ hz1) & HMASK];
    uint32_t u6 = tab[(hx1 ^ hy1 ^ hz0) & HMASK];
    uint32_t u7 = tab[(hx1 ^ hy1 ^ hz1) & HMASK];

    #define UX(u) __uint_as_float((u) & 0xFFFF0000u)
    #define UY(u) __uint_as_float((u) << 16)

    float wx0 = 1.0f - dx, wy0 = 1.0f - dy, wz0 = 1.0f - dz;

    float c00x = UX(u0) * wx0 + UX(u4) * dx;
    float c00y = UY(u0) * wx0 + UY(u4) * dx;
    float c01x = UX(u1) * wx0 + UX(u5) * dx;
    float c01y = UY(u1) * wx0 + UY(u5) * dx;
    float c10x = UX(u2) * wx0 + UX(u6) * dx;
    float c10y = UY(u2) * wx0 + UY(u6) * dx;
    float c11x = UX(u3) * wx0 + UX(u7) * dx;
    float c11y = UY(u3) * wx0 + UY(u7) * dx;

    #undef UX
    #undef UY

    float c0x = c00x * wy0 + c10x * dy;
    float c0y = c00y * wy0 + c10y * dy;
    float c1x = c01x * wy0 + c11x * dy;
    float c1y = c01y * wy0 + c11y * dy;

    v2f r;
    r.x = c0x * wz0 + c1x * dz;
    r.y = c0y * wz0 + c1y * dz;

    __builtin_nontemporal_store(r, &stage[(size_t)level * npts + n]);
}

// ---------------------------------------------------------------------------
// Phase 2: transpose stage[l][n] -> out[n][l] via LDS.
// Loads: 16 coalesced level-major rows. LDS [256][17] float2 (pad 17 breaks
// the stride-16 bank pattern; write aliasing is 2-way = free). Stores: flat
// index blk*2048 + iter*256 + tid -> 1 KiB contiguous per wave instruction
// (16 full lines) so nt streaming stores are full-line and safe.
__global__ __launch_bounds__(256) void transpose_kernel(
    const v2f* __restrict__ stage, v4f* __restrict__ out4, unsigned int npts)
{
    __shared__ v2f lds[256][17];
    unsigned int tid  = threadIdx.x;
    unsigned int base = blockIdx.x * 256u;

#pragma unroll
    for (int l = 0; l < NLEVELS; ++l)
        lds[tid][l] = __builtin_nontemporal_load(&stage[(size_t)l * npts + base + tid]);

    __syncthreads();

#pragma unroll
    for (int it = 0; it < 8; ++it) {
        unsigned int i = it * 256u + tid;        // 0..2047 within block
        unsigned int p = i >> 3;                 // point within block
        unsigned int k = i & 7u;                 // float4 index within record
        v2f a = lds[p][2 * k];
        v2f c = lds[p][2 * k + 1];
        v4f w; w.x = a.x; w.y = a.y; w.z = c.x; w.w = c.y;
        __builtin_nontemporal_store(w, &out4[(size_t)blockIdx.x * 2048u + i]);
    }
}

// ---------------------------------------------------------------------------
// Fallback (round-1 kernel): direct f32 gathers, used only if ws is too small.
__global__ __launch_bounds__(256) void hashgrid_direct_kernel(
    const float* __restrict__ xyz,
    const float* __restrict__ tables,
    float2* __restrict__ out,
    LevelParams lp,
    unsigned int total)
{
    unsigned int t = blockIdx.x * 256u + threadIdx.x;
    if (t >= total) return;
    unsigned int n = t >> 4;
    unsigned int l = t & 15u;

    float x = xyz[n * 3 + 0], y = xyz[n * 3 + 1], z = xyz[n * 3 + 2];
    float cell = lp.cell[l];
    float fx = floorf(x / cell), fy = floorf(y / cell), fz = floorf(z / cell);
    float mvx = fx * cell, mvy = fy * cell, mvz = fz * cell;
    float dnx = (mvx + cell) - mvx, dny = (mvy + cell) - mvy, dnz = (mvz + cell) - mvz;
    float dx = (x - mvx) * __builtin_amdgcn_rcpf(dnx);
    float dy = (y - mvy) * __builtin_amdgcn_rcpf(dny);
    float dz = (z - mvz) * __builtin_amdgcn_rcpf(dnz);
    unsigned int ix = (unsigned int)(int)fx, iy = (unsigned int)(int)fy, iz = (unsigned int)(int)fz;
    unsigned int hx0 = ix, hx1 = ix + 1u;
    unsigned int hy0 = iy * P1, hy1 = hy0 + P1;
    unsigned int hz0 = iz * P2, hz1 = hz0 + P2;
    const float2* __restrict__ tab = (const float2*)tables + (size_t)l * TSIZE;
    float2 e0 = tab[(hx0 ^ hy0 ^ hz0) & HMASK];
    float2 e1 = tab[(hx0 ^ hy0 ^ hz1) & HMASK];
    float2 e2 = tab[(hx0 ^ hy1 ^ hz0) & HMASK];
    float2 e3 = tab[(hx0 ^ hy1 ^ hz1) & HMASK];
    float2 e4 = tab[(hx1 ^ hy0 ^ hz0) & HMASK];
    float2 e5 = tab[(hx1 ^ hy0 ^ hz1) & HMASK];
    float2 e6 = tab[(hx1 ^ hy1 ^ hz0) & HMASK];
    float2 e7 = tab[(hx1 ^ hy1 ^ hz1) & HMASK];
    float wx0 = 1.0f - dx, wy0 = 1.0f - dy, wz0 = 1.0f - dz;
    float c00x = e0.x * wx0 + e4.x * dx, c00y = e0.y * wx0 + e4.y * dx;
    float c01x = e1.x * wx0 + e5.x * dx, c01y = e1.y * wx0 + e5.y * dx;
    float c10x = e2.x * wx0 + e6.x * dx, c10y = e2.y * wx0 + e6.y * dx;
    float c11x = e3.x * wx0 + e7.x * dx, c11y = e3.y * wx0 + e7.y * dx;
    float c0x = c00x * wy0 + c10x * dy, c0y = c00y * wy0 + c10y * dy;
    float c1x = c01x * wy0 + c11x * dy, c1y = c01y * wy0 + c11y * dy;
    out[t] = make_float2(c0x * wz0 + c1x * dz, c0y * wz0 + c1y * dz);
}

// ---------------------------------------------------------------------------
extern "C" void kernel_launch(void* const* d_in, const int* in_sizes, int n_in,
                              void* d_out, int out_size, void* d_ws, size_t ws_size,
                              hipStream_t stream)
{
    const float* xyz    = (const float*)d_in[0];
    const float* tables = (const float*)d_in[1];

    // Resolutions via the SAME libm calls CPython makes (bit-exact floors).
    LevelParams lp;
    double bg = exp((log(512.0) - log(16.0)) / 15.0);
    for (int i = 0; i < NLEVELS; ++i) {
        int res = (int)floor(16.0 * pow(bg, (double)i));
        lp.cell[i] = 1.0f / (float)res;
    }

    unsigned int npts = (unsigned int)(in_sizes[0] / 3);
    size_t tabBytes   = (size_t)NLEVELS * TSIZE * 4u;         // 32 MiB
    size_t stageBytes = (size_t)npts * NLEVELS * sizeof(v2f); // 128 MiB

    if (ws_size >= tabBytes + stageBytes && (npts & 255u) == 0u) {
        uint32_t* tab16 = (uint32_t*)d_ws;
        v2f* stage = (v2f*)((char*)d_ws + tabBytes);

        unsigned int nEntries = NLEVELS * TSIZE;
        hipLaunchKernelGGL(convert_tables_kernel,
                           dim3((nEntries + 255u) / 256u), dim3(256), 0, stream,
                           (const v2f*)tables, tab16, nEntries);

        unsigned int chunks = npts / 256u;                  // 4096
        hipLaunchKernelGGL(hashgrid_compute_kernel,
                           dim3(NLEVELS * chunks), dim3(256), 0, stream,
                           xyz, tab16, stage, lp, npts);

        hipLaunchKernelGGL(transpose_kernel,
                           dim3(chunks), dim3(256), 0, stream,
                           stage, (v4f*)d_out, npts);
    } else {
        unsigned int total = npts * (unsigned int)NLEVELS;
        hipLaunchKernelGGL(hashgrid_direct_kernel,
                           dim3((total + 255u) / 256u), dim3(256), 0, stream,
                           xyz, tables, (float2*)d_out, lp, total);
    }
}